// Round 5
// baseline (180.677 us; speedup 1.0000x reference)
//
#include <hip/hip_runtime.h>
#include <math.h>

// Problem constants (from reference):
//   N=32, C=1, H=512, W=1024 -> HW = 524288 per batch row
//   SAMPLE_NUM = 5000 pairs per row -> 160000 pairs total
//   SIGMA = 0.03, ALPHA = 1.0, EPS = 1e-6, LOSS_WEIGHT = 1.0
#define SAMPLE_NUM 5000
#define HWSZ (512 * 1024)
#define SIGMA_F 0.03f
#define EPS_F 1e-6f
#define BLOCK 256

// R5 design notes:
//  - R3/R4 established: not BW-bound (warm==cold), atomics were the 45 us
//    fixed cost (removed in R4 -> kernels below harness-op noise floor).
//  - Remaining ~30 us is gather LATENCY: 3-deep chain (idx -> mask -> data,
//    last round exec-masked so it can't issue early) with only 2500 waves.
//  - Fix: 2 threads per pair (thread = pair,side). Chain is idx -> {mask,
//    targ, pred} all INDEPENDENT (depth 2), zero wasted gathers, and 5000
//    waves (2x TLP). Partner values via __shfl_xor(.,1); even lane does the
//    pair math.

template <bool MASK_I32>
__device__ __forceinline__ void
side_body(const float* __restrict__ pred, const float* __restrict__ targ,
          const void* __restrict__ mask_raw, const int* __restrict__ idxA,
          const int* __restrict__ idxB, int total, float& eq_sum,
          float& uneq_sum, float& valid) {
  const float hi = 1.0f + SIGMA_F;
  const float lo = 1.0f / (1.0f + SIGMA_F);
  const int* m32 = (const int*)mask_raw;
  const unsigned char* m8 = (const unsigned char*)mask_raw;

  const int t = blockIdx.x * BLOCK + threadIdx.x;
  const int pair = t >> 1;
  const int side = t & 1;  // 0 = A, 1 = B
  if (pair >= total) return;

  const int n = pair / SAMPLE_NUM;  // magic-mul division
  const long long base = (long long)n * HWSZ;
  // Even lanes read consecutive idxA, odd lanes consecutive idxB:
  // 2 coalesced 128B transactions per wave.
  const int idx = side ? idxB[pair] : idxA[pair];
  const long long off = base + idx;

  // --- 3 independent gathers (depth-2 chain from idx) ---
  const int mv = MASK_I32 ? m32[off] : (int)m8[off];
  const float tv = targ[off];
  const float pv = pred[off];

  // Exchange with partner lane (pair sides are adjacent lanes).
  const int m_o = __shfl_xor(mv, 1, 64);
  const float t_o = __shfl_xor(tv, 1, 64);
  const float p_o = __shfl_xor(pv, 1, 64);

  if (side == 0) {  // even lane computes the pair
    if (mv && m_o) {
      valid += 1.0f;
      const float ratio = tv / (t_o + EPS_F);  // tA / (tB + eps)
      if (ratio < hi && ratio > lo) {
        const float d = pv - p_o;  // iA - iB
        eq_sum += d * d;           // ALPHA == 1.0
      } else {
        const float label = (ratio >= hi) ? 1.0f : -1.0f;
        const float x = (p_o - pv) * label;  // (iB - iA) * label
        uneq_sum += (x > 20.0f) ? x : log1pf(expf(x));
      }
    }
  }
}

// Kernel 1: per-block partials -> ws[3*blockIdx + {0,1,2}] (plain stores).
__global__ void __launch_bounds__(BLOCK)
ranking_loss_partial(const float* __restrict__ pred,
                     const float* __restrict__ targ,
                     const void* __restrict__ mask_raw,
                     const int* __restrict__ idxA,
                     const int* __restrict__ idxB,
                     float* __restrict__ ws, int total) {
  // Mask layout detection (thread-uniform). int32 bools: every word is 0/1.
  // Byte bools: uint32 view >1 with P=7/8 per word; 32 words -> P_err=8^-32.
  const unsigned int* mw = (const unsigned int*)mask_raw;
  bool mask_is_i32 = true;
  #pragma unroll
  for (int w = 0; w < 32; ++w) {
    if (mw[w] > 1u) mask_is_i32 = false;
  }

  float eq_sum = 0.0f, uneq_sum = 0.0f, valid = 0.0f;
  if (mask_is_i32) {
    side_body<true>(pred, targ, mask_raw, idxA, idxB, total, eq_sum, uneq_sum,
                    valid);
  } else {
    side_body<false>(pred, targ, mask_raw, idxA, idxB, total, eq_sum,
                     uneq_sum, valid);
  }

  // Wave-64 shuffle reduction
  #pragma unroll
  for (int off = 32; off > 0; off >>= 1) {
    eq_sum   += __shfl_down(eq_sum, off, 64);
    uneq_sum += __shfl_down(uneq_sum, off, 64);
    valid    += __shfl_down(valid, off, 64);
  }

  __shared__ float s_eq[4], s_un[4], s_va[4];
  const int lane = threadIdx.x & 63;
  const int wave = threadIdx.x >> 6;
  if (lane == 0) {
    s_eq[wave] = eq_sum;
    s_un[wave] = uneq_sum;
    s_va[wave] = valid;
  }
  __syncthreads();

  if (threadIdx.x == 0) {
    float e = 0.0f, u = 0.0f, v = 0.0f;
    #pragma unroll
    for (int w = 0; w < BLOCK / 64; ++w) {
      e += s_eq[w];
      u += s_un[w];
      v += s_va[w];
    }
    float* slot = ws + 3 * blockIdx.x;
    slot[0] = e;
    slot[1] = u;
    slot[2] = v;
  }
}

// Kernel 2: single block reduces all per-block slots and writes the scalar.
__global__ void __launch_bounds__(BLOCK)
ranking_loss_finalize(const float* __restrict__ ws, float* __restrict__ out,
                      int nblocks) {
  float e = 0.0f, u = 0.0f, v = 0.0f;
  for (int s = threadIdx.x; s < nblocks; s += BLOCK) {
    e += ws[3 * s + 0];
    u += ws[3 * s + 1];
    v += ws[3 * s + 2];
  }
  #pragma unroll
  for (int off = 32; off > 0; off >>= 1) {
    e += __shfl_down(e, off, 64);
    u += __shfl_down(u, off, 64);
    v += __shfl_down(v, off, 64);
  }
  __shared__ float s_e[4], s_u[4], s_v[4];
  const int lane = threadIdx.x & 63;
  const int wave = threadIdx.x >> 6;
  if (lane == 0) {
    s_e[wave] = e;
    s_u[wave] = u;
    s_v[wave] = v;
  }
  __syncthreads();
  if (threadIdx.x == 0) {
    float te = 0.0f, tu = 0.0f, tv = 0.0f;
    #pragma unroll
    for (int w = 0; w < BLOCK / 64; ++w) {
      te += s_e[w];
      tu += s_u[w];
      tv += s_v[w];
    }
    out[0] = (te + tu) / (tv + EPS_F);  // ALPHA=1, LOSS_WEIGHT=1
  }
}

extern "C" void kernel_launch(void* const* d_in, const int* in_sizes, int n_in,
                              void* d_out, int out_size, void* d_ws,
                              size_t ws_size, hipStream_t stream) {
  const float* pred = (const float*)d_in[0];
  const float* targ = (const float*)d_in[1];
  const void* mask = d_in[2];  // bool array; layout detected on device
  const int* idxA = (const int*)d_in[3];
  const int* idxB = (const int*)d_in[4];
  float* out = (float*)d_out;
  float* ws = (float*)d_ws;

  const int total = in_sizes[3];  // N * SAMPLE_NUM = 160000

  // 2 threads per pair: 320000 threads = 1250 blocks of 256 exactly.
  const int grid = (2 * total + BLOCK - 1) / BLOCK;

  // Every ws slot is written unconditionally by kernel 1 -> no memset needed.
  ranking_loss_partial<<<grid, BLOCK, 0, stream>>>(pred, targ, mask, idxA,
                                                   idxB, ws, total);
  ranking_loss_finalize<<<1, BLOCK, 0, stream>>>(ws, out, grid);
}

// Round 6
// 170.696 us; speedup vs baseline: 1.0585x; 1.0585x over previous
//
#include <hip/hip_runtime.h>
#include <math.h>

// Problem constants (from reference):
//   N=32, C=1, H=512, W=1024 -> HW = 524288 per batch row
//   SAMPLE_NUM = 5000 pairs per row -> 160000 pairs total
//   SIGMA = 0.03, ALPHA = 1.0, EPS = 1e-6, LOSS_WEIGHT = 1.0
#define SAMPLE_NUM 5000
#define HWSZ (512 * 1024)
#define SIGMA_F 0.03f
#define EPS_F 1e-6f
#define BLOCK 256

// R6 design notes (measured ladder):
//  - R3 vs R4: removing 2500 same-line device atomics: 70 -> ~28 us. Done.
//  - R4 vs R5 (controlled): 2x transactions + 2x TLP = WORSE (28 -> 42 us).
//    => bottleneck is random-gather TRANSACTION RATE (~30-40 cy per 128B
//    line per CU), not latency-TLP. Minimize transactions above all.
//  - R6: R5's 2-thread/pair shape (depth-2 chain, 5000 waves, coalesced idx)
//    with R4's CONDITIONAL data gathers. cm = mv && partner_mask is
//    pair-symmetric, so both lanes of a pair agree -> exec-masked lanes
//    issue no transactions, and the post-if shuffles have all lanes active.
//    Transactions: 320k mask + 160k data = 480k (same as R4, 2x its TLP).

template <bool MASK_I32>
__device__ __forceinline__ void
side_body(const float* __restrict__ pred, const float* __restrict__ targ,
          const void* __restrict__ mask_raw, const int* __restrict__ idxA,
          const int* __restrict__ idxB, int total, float& eq_sum,
          float& uneq_sum, float& valid) {
  const float hi = 1.0f + SIGMA_F;
  const float lo = 1.0f / (1.0f + SIGMA_F);
  const int* m32 = (const int*)mask_raw;
  const unsigned char* m8 = (const unsigned char*)mask_raw;

  const int t = blockIdx.x * BLOCK + threadIdx.x;
  const int pair = t >> 1;
  const int side = t & 1;  // 0 = A, 1 = B
  if (pair >= total) return;  // grid is exact (320000 = 1250*256)

  const int n = pair / SAMPLE_NUM;  // magic-mul division
  const long long base = (long long)n * HWSZ;
  // Even lanes read consecutive idxA, odd lanes consecutive idxB:
  // coalesced (2 lines per array per wave).
  const int idx = side ? idxB[pair] : idxA[pair];
  const long long off = base + idx;

  // Round 2: one mask gather per side (320k total).
  const int mv = MASK_I32 ? m32[off] : (int)m8[off];
  const int m_o = __shfl_xor(mv, 1, 64);
  const bool cm = (mv != 0) && (m_o != 0);  // pair-symmetric

  // Round 3: data gathers only for valid pairs (~25% of lanes issue).
  float tv = 0.0f, pv = 0.0f;
  if (cm) {
    tv = targ[off];
    pv = pred[off];
  }
  const float t_o = __shfl_xor(tv, 1, 64);  // all lanes active here
  const float p_o = __shfl_xor(pv, 1, 64);

  if (side == 0 && cm) {  // even lane computes the pair
    valid += 1.0f;
    const float ratio = tv / (t_o + EPS_F);  // tA / (tB + eps)
    if (ratio < hi && ratio > lo) {
      const float d = pv - p_o;  // iA - iB
      eq_sum += d * d;           // ALPHA == 1.0
    } else {
      const float label = (ratio >= hi) ? 1.0f : -1.0f;
      const float x = (p_o - pv) * label;  // (iB - iA) * label
      uneq_sum += (x > 20.0f) ? x : log1pf(expf(x));
    }
  }
}

// Kernel 1: per-block partials -> ws[3*blockIdx + {0,1,2}] (plain stores).
__global__ void __launch_bounds__(BLOCK)
ranking_loss_partial(const float* __restrict__ pred,
                     const float* __restrict__ targ,
                     const void* __restrict__ mask_raw,
                     const int* __restrict__ idxA,
                     const int* __restrict__ idxB,
                     float* __restrict__ ws, int total) {
  // Mask layout detection (thread-uniform). int32 bools: every word is 0/1.
  // Byte bools: uint32 view >1 with P=7/8 per word; 32 words -> P_err=8^-32.
  const unsigned int* mw = (const unsigned int*)mask_raw;
  bool mask_is_i32 = true;
  #pragma unroll
  for (int w = 0; w < 32; ++w) {
    if (mw[w] > 1u) mask_is_i32 = false;
  }

  float eq_sum = 0.0f, uneq_sum = 0.0f, valid = 0.0f;
  if (mask_is_i32) {
    side_body<true>(pred, targ, mask_raw, idxA, idxB, total, eq_sum, uneq_sum,
                    valid);
  } else {
    side_body<false>(pred, targ, mask_raw, idxA, idxB, total, eq_sum,
                     uneq_sum, valid);
  }

  // Wave-64 shuffle reduction
  #pragma unroll
  for (int off = 32; off > 0; off >>= 1) {
    eq_sum   += __shfl_down(eq_sum, off, 64);
    uneq_sum += __shfl_down(uneq_sum, off, 64);
    valid    += __shfl_down(valid, off, 64);
  }

  __shared__ float s_eq[4], s_un[4], s_va[4];
  const int lane = threadIdx.x & 63;
  const int wave = threadIdx.x >> 6;
  if (lane == 0) {
    s_eq[wave] = eq_sum;
    s_un[wave] = uneq_sum;
    s_va[wave] = valid;
  }
  __syncthreads();

  if (threadIdx.x == 0) {
    float e = 0.0f, u = 0.0f, v = 0.0f;
    #pragma unroll
    for (int w = 0; w < BLOCK / 64; ++w) {
      e += s_eq[w];
      u += s_un[w];
      v += s_va[w];
    }
    float* slot = ws + 3 * blockIdx.x;
    slot[0] = e;
    slot[1] = u;
    slot[2] = v;
  }
}

// Kernel 2: single block reduces all per-block slots and writes the scalar.
__global__ void __launch_bounds__(BLOCK)
ranking_loss_finalize(const float* __restrict__ ws, float* __restrict__ out,
                      int nblocks) {
  float e = 0.0f, u = 0.0f, v = 0.0f;
  for (int s = threadIdx.x; s < nblocks; s += BLOCK) {
    e += ws[3 * s + 0];
    u += ws[3 * s + 1];
    v += ws[3 * s + 2];
  }
  #pragma unroll
  for (int off = 32; off > 0; off >>= 1) {
    e += __shfl_down(e, off, 64);
    u += __shfl_down(u, off, 64);
    v += __shfl_down(v, off, 64);
  }
  __shared__ float s_e[4], s_u[4], s_v[4];
  const int lane = threadIdx.x & 63;
  const int wave = threadIdx.x >> 6;
  if (lane == 0) {
    s_e[wave] = e;
    s_u[wave] = u;
    s_v[wave] = v;
  }
  __syncthreads();
  if (threadIdx.x == 0) {
    float te = 0.0f, tu = 0.0f, tv = 0.0f;
    #pragma unroll
    for (int w = 0; w < BLOCK / 64; ++w) {
      te += s_e[w];
      tu += s_u[w];
      tv += s_v[w];
    }
    out[0] = (te + tu) / (tv + EPS_F);  // ALPHA=1, LOSS_WEIGHT=1
  }
}

extern "C" void kernel_launch(void* const* d_in, const int* in_sizes, int n_in,
                              void* d_out, int out_size, void* d_ws,
                              size_t ws_size, hipStream_t stream) {
  const float* pred = (const float*)d_in[0];
  const float* targ = (const float*)d_in[1];
  const void* mask = d_in[2];  // bool array; layout detected on device
  const int* idxA = (const int*)d_in[3];
  const int* idxB = (const int*)d_in[4];
  float* out = (float*)d_out;
  float* ws = (float*)d_ws;

  const int total = in_sizes[3];  // N * SAMPLE_NUM = 160000

  // 2 threads per pair: 320000 threads = 1250 blocks of 256 exactly.
  const int grid = (2 * total + BLOCK - 1) / BLOCK;

  // Every ws slot is written unconditionally by kernel 1 -> no memset needed.
  ranking_loss_partial<<<grid, BLOCK, 0, stream>>>(pred, targ, mask, idxA,
                                                   idxB, ws, total);
  ranking_loss_finalize<<<1, BLOCK, 0, stream>>>(ws, out, grid);
}